// Round 1
// baseline (1141.859 us; speedup 1.0000x reference)
//
#include <hip/hip_runtime.h>
#include <math.h>

// VQ-VAE quantizer. Outputs in d_out (float32, flat, concat):
//   [0]                       loss
//   [1 .. 16777216]           quantized_st, NCHW [16,64,128,128]
//   [16777217]                perplexity
//   [16777218 .. +134217728)  encodings one-hot [262144, 512]
//
// ws layout (floats): [0..511] hist(int, atomics, zeroed via memset)
//                     [512..1023] b_k = ||e_k||^2 (numpy-pairwise exact)
//                     [1024..1535] per-block loss partials
//
// Numerics: argmin must match np fp32 reference exactly -> replicate numpy
// pairwise sums (8-accumulator pattern) for ||x||^2 and ||e||^2, sequential
// fp32 FMA chain for the dot (BLAS sgemm k-order), d = fma(-2,dot,fl(a+b)),
// strict < ascending-k scan (np.argmin first-occurrence ties).

#define NTOK    262144
#define KCODES  512
#define DDIM    64
#define CSTRIDE 16384      // H*W
#define IMG     1048576    // C*H*W
#define BLK     256
#define TOKPB   512        // tokens per block (2 per lane)
#define QOFF    1
#define POFF    16777217
#define EOFF    16777218

__device__ __forceinline__ float np_pairwise_sq64(const float* v) {
    // numpy pairwise_sum over fl(v[i]^2), n=64: 8 strided accumulators then
    // ((r0+r1)+(r2+r3)) + ((r4+r5)+(r6+r7)). No FMA contraction allowed.
    float r[8];
#pragma unroll
    for (int j = 0; j < 8; ++j) r[j] = __fmul_rn(v[j], v[j]);
#pragma unroll
    for (int i = 8; i < 64; i += 8) {
#pragma unroll
        for (int j = 0; j < 8; ++j)
            r[j] = __fadd_rn(r[j], __fmul_rn(v[i + j], v[i + j]));
    }
    float s01 = __fadd_rn(r[0], r[1]);
    float s23 = __fadd_rn(r[2], r[3]);
    float s45 = __fadd_rn(r[4], r[5]);
    float s67 = __fadd_rn(r[6], r[7]);
    return __fadd_rn(__fadd_rn(s01, s23), __fadd_rn(s45, s67));
}

__global__ void vq_bnorm(const float* __restrict__ emb, float* __restrict__ ws) {
    int k = threadIdx.x;                 // 512 threads, 1 block
    const float* e = emb + k * DDIM;
    float v[64];
#pragma unroll
    for (int i = 0; i < 64; ++i) v[i] = e[i];
    ws[512 + k] = np_pairwise_sq64(v);
}

__global__ __launch_bounds__(BLK) void vq_main(const float* __restrict__ in,
                                               const float* __restrict__ emb,
                                               float* __restrict__ out,
                                               float* __restrict__ ws) {
    __shared__ float4 et4[64 * 32];      // e transposed: [d][k-chunk of 128], 32 KB
    __shared__ float  bsh[KCODES];
    __shared__ int    idx_sh[TOKPB];
    __shared__ float  red[BLK / 64];

    float* et = (float*)et4;
    const int tid = threadIdx.x;
    const int blk = blockIdx.x;
    const int tok0 = blk * TOKPB + tid;
    const int tok1 = tok0 + BLK;

    bsh[tid]       = ws[512 + tid];
    bsh[tid + 256] = ws[768 + tid];

    const int b0 = tok0 >> 14, hw0 = tok0 & 16383;
    const int b1 = tok1 >> 14, hw1 = tok1 & 16383;
    const float* p0 = in + (size_t)b0 * IMG + hw0;
    const float* p1 = in + (size_t)b1 * IMG + hw1;

    float x0[64], x1[64];
#pragma unroll
    for (int c = 0; c < 64; ++c) x0[c] = p0[(size_t)c * CSTRIDE];
#pragma unroll
    for (int c = 0; c < 64; ++c) x1[c] = p1[(size_t)c * CSTRIDE];

    const float a0 = np_pairwise_sq64(x0);
    const float a1 = np_pairwise_sq64(x1);

    float dmin0 = 3.402823466e38f, dmin1 = 3.402823466e38f;
    int id0 = 0, id1 = 0;

    for (int kc = 0; kc < 4; ++kc) {
        __syncthreads();
        // stage 128 codes transposed into LDS (global-coalesced float4 reads)
#pragma unroll
        for (int j = 0; j < 8; ++j) {
            int t  = tid + j * 256;      // 0..2047
            int k  = t >> 4;             // 0..127 code within chunk
            int dq = t & 15;             // float4 index along d
            float4 g = ((const float4*)emb)[(size_t)(kc * 128 + k) * 16 + dq];
            et[(dq * 4 + 0) * 128 + k] = g.x;
            et[(dq * 4 + 1) * 128 + k] = g.y;
            et[(dq * 4 + 2) * 128 + k] = g.z;
            et[(dq * 4 + 3) * 128 + k] = g.w;
        }
        __syncthreads();

        for (int kg = 0; kg < 32; ++kg) {
            float a00 = 0.f, a01 = 0.f, a02 = 0.f, a03 = 0.f;
            float a10 = 0.f, a11 = 0.f, a12 = 0.f, a13 = 0.f;
#pragma unroll
            for (int d = 0; d < 64; ++d) {
                const float4 ev = et4[d * 32 + kg];   // broadcast read
                a00 = fmaf(x0[d], ev.x, a00);
                a01 = fmaf(x0[d], ev.y, a01);
                a02 = fmaf(x0[d], ev.z, a02);
                a03 = fmaf(x0[d], ev.w, a03);
                a10 = fmaf(x1[d], ev.x, a10);
                a11 = fmaf(x1[d], ev.y, a11);
                a12 = fmaf(x1[d], ev.z, a12);
                a13 = fmaf(x1[d], ev.w, a13);
            }
            const int kb = kc * 128 + kg * 4;
            {
                float t = __fadd_rn(a0, bsh[kb + 0]); float dd = fmaf(-2.0f, a00, t);
                if (dd < dmin0) { dmin0 = dd; id0 = kb + 0; }
                t = __fadd_rn(a0, bsh[kb + 1]); dd = fmaf(-2.0f, a01, t);
                if (dd < dmin0) { dmin0 = dd; id0 = kb + 1; }
                t = __fadd_rn(a0, bsh[kb + 2]); dd = fmaf(-2.0f, a02, t);
                if (dd < dmin0) { dmin0 = dd; id0 = kb + 2; }
                t = __fadd_rn(a0, bsh[kb + 3]); dd = fmaf(-2.0f, a03, t);
                if (dd < dmin0) { dmin0 = dd; id0 = kb + 3; }
            }
            {
                float t = __fadd_rn(a1, bsh[kb + 0]); float dd = fmaf(-2.0f, a10, t);
                if (dd < dmin1) { dmin1 = dd; id1 = kb + 0; }
                t = __fadd_rn(a1, bsh[kb + 1]); dd = fmaf(-2.0f, a11, t);
                if (dd < dmin1) { dmin1 = dd; id1 = kb + 1; }
                t = __fadd_rn(a1, bsh[kb + 2]); dd = fmaf(-2.0f, a12, t);
                if (dd < dmin1) { dmin1 = dd; id1 = kb + 2; }
                t = __fadd_rn(a1, bsh[kb + 3]); dd = fmaf(-2.0f, a13, t);
                if (dd < dmin1) { dmin1 = dd; id1 = kb + 3; }
            }
        }
    }

    idx_sh[tid]       = id0;
    idx_sh[tid + 256] = id1;
    atomicAdd((int*)ws + id0, 1);
    atomicAdd((int*)ws + id1, 1);

    // quantized_st = fl(x + fl(q - x)), NCHW coalesced stores; loss partials
    float lsum = 0.f;
    {
        const float4* e0 = (const float4*)(emb + (size_t)id0 * DDIM);
        float* q0 = out + QOFF + (size_t)b0 * IMG + hw0;
#pragma unroll
        for (int cq = 0; cq < 16; ++cq) {
            float4 q = e0[cq];
            float d;
            d = __fsub_rn(q.x, x0[cq*4+0]); lsum = __fadd_rn(lsum, __fmul_rn(d,d)); q0[(size_t)(cq*4+0)*CSTRIDE] = __fadd_rn(x0[cq*4+0], d);
            d = __fsub_rn(q.y, x0[cq*4+1]); lsum = __fadd_rn(lsum, __fmul_rn(d,d)); q0[(size_t)(cq*4+1)*CSTRIDE] = __fadd_rn(x0[cq*4+1], d);
            d = __fsub_rn(q.z, x0[cq*4+2]); lsum = __fadd_rn(lsum, __fmul_rn(d,d)); q0[(size_t)(cq*4+2)*CSTRIDE] = __fadd_rn(x0[cq*4+2], d);
            d = __fsub_rn(q.w, x0[cq*4+3]); lsum = __fadd_rn(lsum, __fmul_rn(d,d)); q0[(size_t)(cq*4+3)*CSTRIDE] = __fadd_rn(x0[cq*4+3], d);
        }
    }
    {
        const float4* e1 = (const float4*)(emb + (size_t)id1 * DDIM);
        float* q1 = out + QOFF + (size_t)b1 * IMG + hw1;
#pragma unroll
        for (int cq = 0; cq < 16; ++cq) {
            float4 q = e1[cq];
            float d;
            d = __fsub_rn(q.x, x1[cq*4+0]); lsum = __fadd_rn(lsum, __fmul_rn(d,d)); q1[(size_t)(cq*4+0)*CSTRIDE] = __fadd_rn(x1[cq*4+0], d);
            d = __fsub_rn(q.y, x1[cq*4+1]); lsum = __fadd_rn(lsum, __fmul_rn(d,d)); q1[(size_t)(cq*4+1)*CSTRIDE] = __fadd_rn(x1[cq*4+1], d);
            d = __fsub_rn(q.z, x1[cq*4+2]); lsum = __fadd_rn(lsum, __fmul_rn(d,d)); q1[(size_t)(cq*4+2)*CSTRIDE] = __fadd_rn(x1[cq*4+2], d);
            d = __fsub_rn(q.w, x1[cq*4+3]); lsum = __fadd_rn(lsum, __fmul_rn(d,d)); q1[(size_t)(cq*4+3)*CSTRIDE] = __fadd_rn(x1[cq*4+3], d);
        }
    }
#pragma unroll
    for (int off = 32; off > 0; off >>= 1) lsum += __shfl_down(lsum, off);
    if ((tid & 63) == 0) red[tid >> 6] = lsum;
    __syncthreads();
    if (tid == 0) ws[1024 + blk] = red[0] + red[1] + red[2] + red[3];

    // encodings: block-contiguous 1 MB region, coalesced float2 stores
    float2* enc = (float2*)(out + EOFF + (size_t)blk * (TOKPB * KCODES));
    const int px = tid * 2;
    for (int i = 0; i < TOKPB; ++i) {
        int ix = idx_sh[i];                       // wave-uniform broadcast
        float2 v;
        v.x = (px     == ix) ? 1.0f : 0.0f;
        v.y = (px + 1 == ix) ? 1.0f : 0.0f;
        enc[(size_t)i * 256 + tid] = v;
    }
}

__global__ void vq_final(float* __restrict__ out, const float* __restrict__ ws) {
    __shared__ float sl[512], sp[512];
    int t = threadIdx.x;                          // 512 threads, 1 block
    sl[t] = ws[1024 + t];
    int cnt = ((const int*)ws)[t];
    float p = (float)cnt * (1.0f / 262144.0f);
    sp[t] = p * logf(p + 1e-10f);
    __syncthreads();
    for (int off = 256; off > 0; off >>= 1) {
        if (t < off) { sl[t] += sl[t + off]; sp[t] += sp[t + off]; }
        __syncthreads();
    }
    if (t == 0) {
        float m = sl[0] * (1.0f / 16777216.0f);   // /2^24 exact
        out[0]    = __fadd_rn(m, __fmul_rn(0.25f, m));  // q_latent + 0.25*e_latent
        out[POFF] = expf(-sp[0]);
    }
}

extern "C" void kernel_launch(void* const* d_in, const int* in_sizes, int n_in,
                              void* d_out, int out_size, void* d_ws, size_t ws_size,
                              hipStream_t stream) {
    const float* in  = (const float*)d_in[0];
    const float* emb = (const float*)d_in[1];
    float* out = (float*)d_out;
    float* ws  = (float*)d_ws;

    hipMemsetAsync(d_ws, 0, 512 * sizeof(int), stream);          // histogram
    hipLaunchKernelGGL(vq_bnorm, dim3(1),   dim3(512), 0, stream, emb, ws);
    hipLaunchKernelGGL(vq_main,  dim3(512), dim3(BLK), 0, stream, in, emb, out, ws);
    hipLaunchKernelGGL(vq_final, dim3(1),   dim3(512), 0, stream, out, ws);
}